// Round 1
// baseline (112.928 us; speedup 1.0000x reference)
//
#include <hip/hip_runtime.h>
#include <hip/hip_bf16.h>

// Problem dims (fixed): B=8, Q=256, K=256, D=256, H=256, DV=512
#define B_  8
#define Q_  256
#define K_  256
#define D_  256
#define H_  256
#define DV_ 512
#define QB  8            // q-rows per attn block

#define SCALE_2LOG2E 2.8853900817779268f   // 2*log2(e): exp(2x) = 2^(x*this)
#define LOG2E_F      1.4426950408889634f

// ---------------------------------------------------------------------------
// Kernel 1: projections.
//   qh [B][Q][H]  = (queries @ W_q) * 2log2e         (row-major)
//   khT[B][H][K]  = (keys    @ W_k)^T * 2log2e       (transposed for coalesced
//                                                     per-h reads in kernel 2)
// grid (4,4,16): x -> 64-chunk of Q (or K), y -> 64-chunk of H, z: b + 8*path
// ---------------------------------------------------------------------------
__global__ __launch_bounds__(256) void proj_kernel(
    const float* __restrict__ queries, const float* __restrict__ keys,
    const float* __restrict__ Wq, const float* __restrict__ Wk,
    float* __restrict__ qh, float* __restrict__ khT) {
  const int tid = threadIdx.x;
  const int m0 = blockIdx.x * 64;          // q-rows (qpath) or k-cols (kpath)
  const int h0 = blockIdx.y * 64;
  const int b  = blockIdx.z & 7;
  const bool kpath = blockIdx.z >= 8;

  __shared__ float As[64][68];             // qpath: A[q][d]   kpath: Wk^T[h][d]
  __shared__ float Bs[64][68];             // qpath: Wq[d][h]  kpath: keys^T[d][k]

  const int lr = tid >> 4;                 // 0..15 (load row)
  const int lc = (tid & 15) << 2;          // 0,4,...,60 (load col, float4)
  const int r0 = lr << 2;                  // compute micro-tile rows
  const int c0 = lc;                       // compute micro-tile cols

  float acc[4][4] = {};

  for (int kk = 0; kk < D_; kk += 64) {
    if (!kpath) {
      #pragma unroll
      for (int i = 0; i < 4; i++) {
        const int row = lr + i * 16;
        float4 va = *(const float4*)&queries[((size_t)(b * Q_ + m0 + row)) * D_ + kk + lc];
        *(float4*)&As[row][lc] = va;
        float4 vb = *(const float4*)&Wq[((size_t)(kk + row)) * H_ + h0 + lc];
        *(float4*)&Bs[row][lc] = vb;
      }
    } else {
      #pragma unroll
      for (int i = 0; i < 4; i++) {
        const int row = lr + i * 16;
        // As[h][d] <- Wk[kk+row][h0+lc+j]   (row = d-offset)
        float4 va = *(const float4*)&Wk[((size_t)(kk + row)) * H_ + h0 + lc];
        As[lc + 0][row] = va.x; As[lc + 1][row] = va.y;
        As[lc + 2][row] = va.z; As[lc + 3][row] = va.w;
        // Bs[d][k] <- keys[b][m0+row][kk+lc+j]   (row = k-offset)
        float4 vb = *(const float4*)&keys[((size_t)(b * K_ + m0 + row)) * D_ + kk + lc];
        Bs[lc + 0][row] = vb.x; Bs[lc + 1][row] = vb.y;
        Bs[lc + 2][row] = vb.z; Bs[lc + 3][row] = vb.w;
      }
    }
    __syncthreads();

    #pragma unroll 8
    for (int d = 0; d < 64; d++) {
      float4 bv = *(const float4*)&Bs[d][c0];
      float av0 = As[r0 + 0][d], av1 = As[r0 + 1][d];
      float av2 = As[r0 + 2][d], av3 = As[r0 + 3][d];
      acc[0][0] = fmaf(av0, bv.x, acc[0][0]); acc[0][1] = fmaf(av0, bv.y, acc[0][1]);
      acc[0][2] = fmaf(av0, bv.z, acc[0][2]); acc[0][3] = fmaf(av0, bv.w, acc[0][3]);
      acc[1][0] = fmaf(av1, bv.x, acc[1][0]); acc[1][1] = fmaf(av1, bv.y, acc[1][1]);
      acc[1][2] = fmaf(av1, bv.z, acc[1][2]); acc[1][3] = fmaf(av1, bv.w, acc[1][3]);
      acc[2][0] = fmaf(av2, bv.x, acc[2][0]); acc[2][1] = fmaf(av2, bv.y, acc[2][1]);
      acc[2][2] = fmaf(av2, bv.z, acc[2][2]); acc[2][3] = fmaf(av2, bv.w, acc[2][3]);
      acc[3][0] = fmaf(av3, bv.x, acc[3][0]); acc[3][1] = fmaf(av3, bv.y, acc[3][1]);
      acc[3][2] = fmaf(av3, bv.z, acc[3][2]); acc[3][3] = fmaf(av3, bv.w, acc[3][3]);
    }
    __syncthreads();
  }

  if (!kpath) {
    #pragma unroll
    for (int i = 0; i < 4; i++) {
      float4 v = make_float4(acc[i][0] * SCALE_2LOG2E, acc[i][1] * SCALE_2LOG2E,
                             acc[i][2] * SCALE_2LOG2E, acc[i][3] * SCALE_2LOG2E);
      *(float4*)&qh[((size_t)(b * Q_ + m0 + r0 + i)) * H_ + h0 + c0] = v;
    }
  } else {
    // C[h][k] = sum_d Wk[d][h]*keys[k][d] = khT[h][k]
    #pragma unroll
    for (int i = 0; i < 4; i++) {
      float4 v = make_float4(acc[i][0] * SCALE_2LOG2E, acc[i][1] * SCALE_2LOG2E,
                             acc[i][2] * SCALE_2LOG2E, acc[i][3] * SCALE_2LOG2E);
      *(float4*)&khT[((size_t)(b * H_ + h0 + r0 + i)) * K_ + m0 + c0] = v;
    }
  }
}

// ---------------------------------------------------------------------------
// Kernel 2: fused scores + softmax + PV.
//   score'[b,q,k] = -2 * sum_h w_v[h] / (2^(qh'+kh') + 1)
//   (the +sum(w_v) constant is dropped: softmax is shift-invariant)
// One block (256 thr) per (b, 8 q-rows); thread t owns k = t.
// ---------------------------------------------------------------------------
__global__ __launch_bounds__(256) void attn_kernel(
    const float* __restrict__ qh, const float* __restrict__ khT,
    const float* __restrict__ wv, const float* __restrict__ values,
    float* __restrict__ out) {
  const int t  = threadIdx.x;
  const int b  = blockIdx.y;
  const int q0 = blockIdx.x * QB;

  __shared__ float qh_lds[QB][H_];
  __shared__ float wv_lds[H_];
  __shared__ float attn_lds[QB][K_];
  __shared__ float redmax[QB];
  __shared__ float redsum[QB];

  #pragma unroll
  for (int qq = 0; qq < QB; qq++)
    qh_lds[qq][t] = qh[((size_t)(b * Q_ + q0 + qq)) * H_ + t];
  wv_lds[t] = wv[t];
  __syncthreads();

  // ---- scores: s2[qq] = sum_h wv[h] * rcp(2^(qh'+kh') + 1) ----
  float s2[QB] = {};
  const float* kp = khT + (size_t)b * H_ * K_ + t;
  #pragma unroll 2
  for (int h = 0; h < H_; h++) {
    float khv = kp[(size_t)h * K_];
    float wvh = wv_lds[h];
    #pragma unroll
    for (int qq = 0; qq < QB; qq++) {
      float x = qh_lds[qq][h] + khv;
      float e = __builtin_amdgcn_exp2f(x);
      float r = __builtin_amdgcn_rcpf(e + 1.0f);
      s2[qq] = fmaf(wvh, r, s2[qq]);
    }
  }

  float sc[QB];
  #pragma unroll
  for (int qq = 0; qq < QB; qq++) {
    sc[qq] = -2.0f * s2[qq];
    attn_lds[qq][t] = sc[qq];
  }
  __syncthreads();

  // ---- softmax over k (256 threads = 8 rows x 32 reducers) ----
  const int qr = t >> 5, j = t & 31;
  float m = -1e30f;
  #pragma unroll
  for (int i = 0; i < 8; i++) m = fmaxf(m, attn_lds[qr][j + (i << 5)]);
  #pragma unroll
  for (int mask = 16; mask >= 1; mask >>= 1) m = fmaxf(m, __shfl_xor(m, mask));
  if (j == 0) redmax[qr] = m;
  __syncthreads();

  float ev[QB];
  #pragma unroll
  for (int qq = 0; qq < QB; qq++) {
    ev[qq] = __builtin_amdgcn_exp2f((sc[qq] - redmax[qq]) * LOG2E_F);
    attn_lds[qq][t] = ev[qq];
  }
  __syncthreads();

  float s = 0.0f;
  #pragma unroll
  for (int i = 0; i < 8; i++) s += attn_lds[qr][j + (i << 5)];
  #pragma unroll
  for (int mask = 16; mask >= 1; mask >>= 1) s += __shfl_xor(s, mask);
  if (j == 0) redsum[qr] = s;
  __syncthreads();

  // ---- PV: out[b][q0+qq][dv] = (1/sum) * sum_k e_k * values[b][k][dv] ----
  float acc0[QB] = {}, acc1[QB] = {};
  const float* vp = values + (size_t)b * K_ * DV_ + t;
  #pragma unroll 2
  for (int k = 0; k < K_; k++) {
    float v0 = vp[(size_t)k * DV_];
    float v1 = vp[(size_t)k * DV_ + 256];
    #pragma unroll
    for (int qq = 0; qq < QB; qq++) {
      float a = attn_lds[qq][k];
      acc0[qq] = fmaf(a, v0, acc0[qq]);
      acc1[qq] = fmaf(a, v1, acc1[qq]);
    }
  }
  #pragma unroll
  for (int qq = 0; qq < QB; qq++) {
    float rs = __builtin_amdgcn_rcpf(redsum[qq]);
    size_t o = ((size_t)(b * Q_ + q0 + qq)) * DV_ + t;
    out[o] = acc0[qq] * rs;
    out[o + 256] = acc1[qq] * rs;
  }
}

extern "C" void kernel_launch(void* const* d_in, const int* in_sizes, int n_in,
                              void* d_out, int out_size, void* d_ws, size_t ws_size,
                              hipStream_t stream) {
  const float* queries = (const float*)d_in[0];  // [8,256,256]
  const float* keys    = (const float*)d_in[1];  // [8,256,256]
  const float* values  = (const float*)d_in[2];  // [8,256,512]
  const float* W_q     = (const float*)d_in[3];  // [256,256]
  const float* W_k     = (const float*)d_in[4];  // [256,256]
  const float* w_v     = (const float*)d_in[5];  // [256]
  float* out = (float*)d_out;

  float* qh  = (float*)d_ws;                     // [8][256][256] = 2 MB
  float* khT = qh + (size_t)B_ * Q_ * H_;        // [8][256][256] = 2 MB

  dim3 pgrid(4, 4, 16), pblk(256);
  proj_kernel<<<pgrid, pblk, 0, stream>>>(queries, keys, W_q, W_k, qh, khT);

  dim3 agrid(Q_ / QB, B_), ablk(256);
  attn_kernel<<<agrid, ablk, 0, stream>>>(qh, khT, w_v, values, out);
}

// Round 2
// 78.410 us; speedup vs baseline: 1.4402x; 1.4402x over previous
//
#include <hip/hip_runtime.h>
#include <hip/hip_bf16.h>

// Problem dims (fixed): B=8, Q=256, K=256, D=256, H=256, DV=512
#define B_  8
#define Q_  256
#define K_  256
#define D_  256
#define H_  256
#define DV_ 512
#define QB  2            // q-rows per attn block (small => big grid => occupancy)

#define SCALE_2LOG2E 2.8853900817779268f   // 2*log2(e): exp(2x) = 2^(x*this)
#define LOG2E_F      1.4426950408889634f

// ---------------------------------------------------------------------------
// Kernel 1: projections.
//   qh [B][Q][H]  = (queries @ W_q) * 2log2e         (row-major)
//   khT[B][H][K]  = (keys    @ W_k)^T * 2log2e       (transposed for coalesced
//                                                     per-h reads in kernel 2)
// grid (4,4,16): x -> 64-chunk of Q (or K), y -> 64-chunk of H, z: b + 8*path
// ---------------------------------------------------------------------------
__global__ __launch_bounds__(256) void proj_kernel(
    const float* __restrict__ queries, const float* __restrict__ keys,
    const float* __restrict__ Wq, const float* __restrict__ Wk,
    float* __restrict__ qh, float* __restrict__ khT) {
  const int tid = threadIdx.x;
  const int m0 = blockIdx.x * 64;          // q-rows (qpath) or k-cols (kpath)
  const int h0 = blockIdx.y * 64;
  const int b  = blockIdx.z & 7;
  const bool kpath = blockIdx.z >= 8;

  __shared__ float As[64][68];             // qpath: A[q][d]   kpath: Wk^T[h][d]
  __shared__ float Bs[64][68];             // qpath: Wq[d][h]  kpath: keys^T[d][k]

  const int lr = tid >> 4;                 // 0..15 (load row)
  const int lc = (tid & 15) << 2;          // 0,4,...,60 (load col, float4)
  const int r0 = lr << 2;                  // compute micro-tile rows
  const int c0 = lc;                       // compute micro-tile cols

  float acc[4][4] = {};

  for (int kk = 0; kk < D_; kk += 64) {
    if (!kpath) {
      #pragma unroll
      for (int i = 0; i < 4; i++) {
        const int row = lr + i * 16;
        float4 va = *(const float4*)&queries[((size_t)(b * Q_ + m0 + row)) * D_ + kk + lc];
        *(float4*)&As[row][lc] = va;
        float4 vb = *(const float4*)&Wq[((size_t)(kk + row)) * H_ + h0 + lc];
        *(float4*)&Bs[row][lc] = vb;
      }
    } else {
      #pragma unroll
      for (int i = 0; i < 4; i++) {
        const int row = lr + i * 16;
        // As[h][d] <- Wk[kk+row][h0+lc+j]   (row = d-offset)
        float4 va = *(const float4*)&Wk[((size_t)(kk + row)) * H_ + h0 + lc];
        As[lc + 0][row] = va.x; As[lc + 1][row] = va.y;
        As[lc + 2][row] = va.z; As[lc + 3][row] = va.w;
        // Bs[d][k] <- keys[b][m0+row][kk+lc+j]   (row = k-offset)
        float4 vb = *(const float4*)&keys[((size_t)(b * K_ + m0 + row)) * D_ + kk + lc];
        Bs[lc + 0][row] = vb.x; Bs[lc + 1][row] = vb.y;
        Bs[lc + 2][row] = vb.z; Bs[lc + 3][row] = vb.w;
      }
    }
    __syncthreads();

    #pragma unroll 8
    for (int d = 0; d < 64; d++) {
      float4 bv = *(const float4*)&Bs[d][c0];
      float av0 = As[r0 + 0][d], av1 = As[r0 + 1][d];
      float av2 = As[r0 + 2][d], av3 = As[r0 + 3][d];
      acc[0][0] = fmaf(av0, bv.x, acc[0][0]); acc[0][1] = fmaf(av0, bv.y, acc[0][1]);
      acc[0][2] = fmaf(av0, bv.z, acc[0][2]); acc[0][3] = fmaf(av0, bv.w, acc[0][3]);
      acc[1][0] = fmaf(av1, bv.x, acc[1][0]); acc[1][1] = fmaf(av1, bv.y, acc[1][1]);
      acc[1][2] = fmaf(av1, bv.z, acc[1][2]); acc[1][3] = fmaf(av1, bv.w, acc[1][3]);
      acc[2][0] = fmaf(av2, bv.x, acc[2][0]); acc[2][1] = fmaf(av2, bv.y, acc[2][1]);
      acc[2][2] = fmaf(av2, bv.z, acc[2][2]); acc[2][3] = fmaf(av2, bv.w, acc[2][3]);
      acc[3][0] = fmaf(av3, bv.x, acc[3][0]); acc[3][1] = fmaf(av3, bv.y, acc[3][1]);
      acc[3][2] = fmaf(av3, bv.z, acc[3][2]); acc[3][3] = fmaf(av3, bv.w, acc[3][3]);
    }
    __syncthreads();
  }

  if (!kpath) {
    #pragma unroll
    for (int i = 0; i < 4; i++) {
      float4 v = make_float4(acc[i][0] * SCALE_2LOG2E, acc[i][1] * SCALE_2LOG2E,
                             acc[i][2] * SCALE_2LOG2E, acc[i][3] * SCALE_2LOG2E);
      *(float4*)&qh[((size_t)(b * Q_ + m0 + r0 + i)) * H_ + h0 + c0] = v;
    }
  } else {
    // C[h][k] = sum_d Wk[d][h]*keys[k][d] = khT[h][k]
    #pragma unroll
    for (int i = 0; i < 4; i++) {
      float4 v = make_float4(acc[i][0] * SCALE_2LOG2E, acc[i][1] * SCALE_2LOG2E,
                             acc[i][2] * SCALE_2LOG2E, acc[i][3] * SCALE_2LOG2E);
      *(float4*)&khT[((size_t)(b * H_ + h0 + r0 + i)) * K_ + m0 + c0] = v;
    }
  }
}

// ---------------------------------------------------------------------------
// Kernel 2: fused scores + softmax + PV.
//   score'[b,q,k] = -2 * sum_h w_v[h] / (2^(qh'+kh') + 1)
//   (the +sum(w_v) constant is dropped: softmax is shift-invariant)
// One block (256 thr = 4 waves) per (b, 2 q-rows): 1024 blocks -> 4 blocks/CU,
// 16 waves/CU. Score phase: thread t owns k=t. PV phase: thread t owns
// dv={2t,2t+1} (float2 loads).
// ---------------------------------------------------------------------------
__global__ __launch_bounds__(256) void attn_kernel(
    const float* __restrict__ qh, const float* __restrict__ khT,
    const float* __restrict__ wv, const float* __restrict__ values,
    float* __restrict__ out) {
  const int t   = threadIdx.x;
  const int b   = blockIdx.y;
  const int q0  = blockIdx.x * QB;
  const int wid = t >> 6;

  __shared__ float qh_lds[QB][H_];
  __shared__ float wv_lds[H_];
  __shared__ float attn_lds[QB][K_];
  __shared__ float pmax[QB][4];
  __shared__ float psum[QB][4];

  #pragma unroll
  for (int qq = 0; qq < QB; qq++)
    qh_lds[qq][t] = qh[((size_t)(b * Q_ + q0 + qq)) * H_ + t];
  wv_lds[t] = wv[t];
  __syncthreads();

  // ---- scores: s2[qq] = sum_h wv[h] * rcp(2^(qh'+kh') + 1), k = t ----
  float s2[QB] = {};
  const float* kp = khT + (size_t)b * H_ * K_ + t;
  #pragma unroll 4
  for (int h = 0; h < H_; h++) {
    float khv = kp[(size_t)h * K_];
    float wvh = wv_lds[h];
    #pragma unroll
    for (int qq = 0; qq < QB; qq++) {
      float x = qh_lds[qq][h] + khv;
      float e = __builtin_amdgcn_exp2f(x);
      float r = __builtin_amdgcn_rcpf(e + 1.0f);
      s2[qq] = fmaf(wvh, r, s2[qq]);
    }
  }

  // ---- softmax over k: per-wave shfl reduce, 4 partials via LDS ----
  float sc[QB];
  #pragma unroll
  for (int qq = 0; qq < QB; qq++) {
    sc[qq] = -2.0f * s2[qq];
    float m = sc[qq];
    #pragma unroll
    for (int mask = 32; mask >= 1; mask >>= 1) m = fmaxf(m, __shfl_xor(m, mask));
    if ((t & 63) == 0) pmax[qq][wid] = m;
  }
  __syncthreads();

  #pragma unroll
  for (int qq = 0; qq < QB; qq++) {
    float mx = fmaxf(fmaxf(pmax[qq][0], pmax[qq][1]), fmaxf(pmax[qq][2], pmax[qq][3]));
    float ev = __builtin_amdgcn_exp2f((sc[qq] - mx) * LOG2E_F);
    attn_lds[qq][t] = ev;
    float s = ev;
    #pragma unroll
    for (int mask = 32; mask >= 1; mask >>= 1) s += __shfl_xor(s, mask);
    if ((t & 63) == 0) psum[qq][wid] = s;
  }
  __syncthreads();

  float rs[QB];
  #pragma unroll
  for (int qq = 0; qq < QB; qq++)
    rs[qq] = __builtin_amdgcn_rcpf(psum[qq][0] + psum[qq][1] + psum[qq][2] + psum[qq][3]);

  // ---- PV: thread t owns dv = {2t, 2t+1}; loop all k ----
  float2 acc[QB];
  #pragma unroll
  for (int qq = 0; qq < QB; qq++) acc[qq] = make_float2(0.f, 0.f);
  const float2* vp = (const float2*)(values + (size_t)b * K_ * DV_) + t;
  #pragma unroll 4
  for (int k = 0; k < K_; k++) {
    float2 v = vp[(size_t)k * (DV_ / 2)];
    #pragma unroll
    for (int qq = 0; qq < QB; qq++) {
      float a = attn_lds[qq][k];
      acc[qq].x = fmaf(a, v.x, acc[qq].x);
      acc[qq].y = fmaf(a, v.y, acc[qq].y);
    }
  }
  #pragma unroll
  for (int qq = 0; qq < QB; qq++) {
    float2 o = make_float2(acc[qq].x * rs[qq], acc[qq].y * rs[qq]);
    *(float2*)&out[((size_t)(b * Q_ + q0 + qq)) * DV_ + 2 * t] = o;
  }
}

extern "C" void kernel_launch(void* const* d_in, const int* in_sizes, int n_in,
                              void* d_out, int out_size, void* d_ws, size_t ws_size,
                              hipStream_t stream) {
  const float* queries = (const float*)d_in[0];  // [8,256,256]
  const float* keys    = (const float*)d_in[1];  // [8,256,256]
  const float* values  = (const float*)d_in[2];  // [8,256,512]
  const float* W_q     = (const float*)d_in[3];  // [256,256]
  const float* W_k     = (const float*)d_in[4];  // [256,256]
  const float* w_v     = (const float*)d_in[5];  // [256]
  float* out = (float*)d_out;

  float* qh  = (float*)d_ws;                     // [8][256][256] = 2 MB
  float* khT = qh + (size_t)B_ * Q_ * H_;        // [8][256][256] = 2 MB

  dim3 pgrid(4, 4, 16), pblk(256);
  proj_kernel<<<pgrid, pblk, 0, stream>>>(queries, keys, W_q, W_k, qh, khT);

  dim3 agrid(Q_ / QB, B_), ablk(256);
  attn_kernel<<<agrid, ablk, 0, stream>>>(qh, khT, w_v, values, out);
}

// Round 3
// 64.860 us; speedup vs baseline: 1.7411x; 1.2089x over previous
//
#include <hip/hip_runtime.h>
#include <hip/hip_bf16.h>

// Problem dims (fixed): B=8, Q=256, K=256, D=256, H=256, DV=512
#define B_  8
#define Q_  256
#define K_  256
#define D_  256
#define H_  256
#define DV_ 512
#define QB  4            // q-rows per attn block

#define SCALE_2LOG2E 2.8853900817779268f   // 2*log2(e): exp(2x) = 2^(x*this)
#define LOG2E_F      1.4426950408889634f

// ---------------------------------------------------------------------------
// Kernel 1: projections.
//   qh [B][Q][H]  = (queries @ W_q) * 2log2e         (row-major)
//   khT[B][H][K]  = (keys    @ W_k)^T * 2log2e       (transposed for coalesced
//                                                     per-h reads in kernel 2)
// grid (4,4,16): x -> 64-chunk of Q (or K), y -> 64-chunk of H, z: b + 8*path
// ---------------------------------------------------------------------------
__global__ __launch_bounds__(256) void proj_kernel(
    const float* __restrict__ queries, const float* __restrict__ keys,
    const float* __restrict__ Wq, const float* __restrict__ Wk,
    float* __restrict__ qh, float* __restrict__ khT) {
  const int tid = threadIdx.x;
  const int m0 = blockIdx.x * 64;          // q-rows (qpath) or k-cols (kpath)
  const int h0 = blockIdx.y * 64;
  const int b  = blockIdx.z & 7;
  const bool kpath = blockIdx.z >= 8;

  __shared__ float As[64][68];             // qpath: A[q][d]   kpath: Wk^T[h][d]
  __shared__ float Bs[64][68];             // qpath: Wq[d][h]  kpath: keys^T[d][k]

  const int lr = tid >> 4;                 // 0..15 (load row)
  const int lc = (tid & 15) << 2;          // 0,4,...,60 (load col, float4)
  const int r0 = lr << 2;                  // compute micro-tile rows
  const int c0 = lc;                       // compute micro-tile cols

  float acc[4][4] = {};

  for (int kk = 0; kk < D_; kk += 64) {
    if (!kpath) {
      #pragma unroll
      for (int i = 0; i < 4; i++) {
        const int row = lr + i * 16;
        float4 va = *(const float4*)&queries[((size_t)(b * Q_ + m0 + row)) * D_ + kk + lc];
        *(float4*)&As[row][lc] = va;
        float4 vb = *(const float4*)&Wq[((size_t)(kk + row)) * H_ + h0 + lc];
        *(float4*)&Bs[row][lc] = vb;
      }
    } else {
      #pragma unroll
      for (int i = 0; i < 4; i++) {
        const int row = lr + i * 16;
        // As[h][d] <- Wk[kk+row][h0+lc+j]   (row = d-offset)
        float4 va = *(const float4*)&Wk[((size_t)(kk + row)) * H_ + h0 + lc];
        As[lc + 0][row] = va.x; As[lc + 1][row] = va.y;
        As[lc + 2][row] = va.z; As[lc + 3][row] = va.w;
        // Bs[d][k] <- keys[b][m0+row][kk+lc+j]   (row = k-offset)
        float4 vb = *(const float4*)&keys[((size_t)(b * K_ + m0 + row)) * D_ + kk + lc];
        Bs[lc + 0][row] = vb.x; Bs[lc + 1][row] = vb.y;
        Bs[lc + 2][row] = vb.z; Bs[lc + 3][row] = vb.w;
      }
    }
    __syncthreads();

    #pragma unroll 8
    for (int d = 0; d < 64; d++) {
      float4 bv = *(const float4*)&Bs[d][c0];
      float av0 = As[r0 + 0][d], av1 = As[r0 + 1][d];
      float av2 = As[r0 + 2][d], av3 = As[r0 + 3][d];
      acc[0][0] = fmaf(av0, bv.x, acc[0][0]); acc[0][1] = fmaf(av0, bv.y, acc[0][1]);
      acc[0][2] = fmaf(av0, bv.z, acc[0][2]); acc[0][3] = fmaf(av0, bv.w, acc[0][3]);
      acc[1][0] = fmaf(av1, bv.x, acc[1][0]); acc[1][1] = fmaf(av1, bv.y, acc[1][1]);
      acc[1][2] = fmaf(av1, bv.z, acc[1][2]); acc[1][3] = fmaf(av1, bv.w, acc[1][3]);
      acc[2][0] = fmaf(av2, bv.x, acc[2][0]); acc[2][1] = fmaf(av2, bv.y, acc[2][1]);
      acc[2][2] = fmaf(av2, bv.z, acc[2][2]); acc[2][3] = fmaf(av2, bv.w, acc[2][3]);
      acc[3][0] = fmaf(av3, bv.x, acc[3][0]); acc[3][1] = fmaf(av3, bv.y, acc[3][1]);
      acc[3][2] = fmaf(av3, bv.z, acc[3][2]); acc[3][3] = fmaf(av3, bv.w, acc[3][3]);
    }
    __syncthreads();
  }

  if (!kpath) {
    #pragma unroll
    for (int i = 0; i < 4; i++) {
      float4 v = make_float4(acc[i][0] * SCALE_2LOG2E, acc[i][1] * SCALE_2LOG2E,
                             acc[i][2] * SCALE_2LOG2E, acc[i][3] * SCALE_2LOG2E);
      *(float4*)&qh[((size_t)(b * Q_ + m0 + r0 + i)) * H_ + h0 + c0] = v;
    }
  } else {
    // C[h][k] = sum_d Wk[d][h]*keys[k][d] = khT[h][k]
    #pragma unroll
    for (int i = 0; i < 4; i++) {
      float4 v = make_float4(acc[i][0] * SCALE_2LOG2E, acc[i][1] * SCALE_2LOG2E,
                             acc[i][2] * SCALE_2LOG2E, acc[i][3] * SCALE_2LOG2E);
      *(float4*)&khT[((size_t)(b * H_ + h0 + r0 + i)) * K_ + m0 + c0] = v;
    }
  }
}

// ---------------------------------------------------------------------------
// Kernel 2: fused scores + softmax + PV.
//   score'[b,q,k] = sum_h (-2*w_v[h]) / (2^(qh'+kh') + 1)   (const term dropped)
// 512 threads = 8 waves per block, QB=4 q-rows, grid (64,8) = 512 blocks
//   -> 2 blocks/CU, 32 waves/CU (100% of wave slots).
// Score phase: h-range split across half-blocks (waves 0-3: h<128, 4-7: h>=128),
//   thread owns k = t&255; partial s2 combined via LDS.
// PV phase: 4-way k-split (t>>7) x float4-dv ownership (t&127), LDS combine.
// ---------------------------------------------------------------------------
__global__ __launch_bounds__(512) void attn_kernel(
    const float* __restrict__ qh, const float* __restrict__ khT,
    const float* __restrict__ wv, const float* __restrict__ values,
    float* __restrict__ out) {
  const int t    = threadIdx.x;
  const int half = t >> 8;      // h-range selector (score phase)
  const int tk   = t & 255;     // owned k column (score phase)
  const int b    = blockIdx.y;
  const int q0   = blockIdx.x * QB;

  __shared__ float qh_lds[QB][H_];        // 4 KB
  __shared__ float wv_lds[H_];            // 1 KB  (holds -2*wv)
  __shared__ float attn_lds[QB][K_];      // 4 KB
  __shared__ float scratch[3 * QB * 512]; // 24 KB: s2 partials / PV partials
  __shared__ float pmax[QB][4];
  __shared__ float psum[QB][4];

  // ---- stage qh rows + wv ----
  const float* qh_src = qh + ((size_t)(b * Q_ + q0)) * H_;
  #pragma unroll
  for (int i = 0; i < 2; i++) ((float*)qh_lds)[t + i * 512] = qh_src[t + i * 512];
  if (t < H_) wv_lds[t] = -2.0f * wv[t];
  __syncthreads();

  // ---- score partials: s2[qq] = sum_{h in my half} (-2 wv[h]) * sigma ----
  float s2[QB] = {};
  const int hbase = half * 128;
  const float* kp = khT + (size_t)b * H_ * K_ + (size_t)hbase * K_ + tk;
  #pragma unroll 2
  for (int hh = 0; hh < 128; hh++) {
    const int h = hbase + hh;
    float khv = kp[(size_t)hh * K_];
    float wvh = wv_lds[h];
    #pragma unroll
    for (int qq = 0; qq < QB; qq++) {
      float x = qh_lds[qq][h] + khv;
      float e = __builtin_amdgcn_exp2f(x);
      float r = __builtin_amdgcn_rcpf(e + 1.0f);
      s2[qq] = fmaf(wvh, r, s2[qq]);
    }
  }
  #pragma unroll
  for (int qq = 0; qq < QB; qq++) scratch[(half * QB + qq) * K_ + tk] = s2[qq];
  __syncthreads();

  // ---- softmax over k (lower half-block only; waves 0-3 own k=tk) ----
  float sc[QB];
  const int wid = t >> 6;
  if (half == 0) {
    #pragma unroll
    for (int qq = 0; qq < QB; qq++) {
      sc[qq] = scratch[qq * K_ + tk] + scratch[(QB + qq) * K_ + tk];
      float m = sc[qq];
      #pragma unroll
      for (int mask = 32; mask >= 1; mask >>= 1) m = fmaxf(m, __shfl_xor(m, mask));
      if ((t & 63) == 0) pmax[qq][wid] = m;
    }
  }
  __syncthreads();
  if (half == 0) {
    #pragma unroll
    for (int qq = 0; qq < QB; qq++) {
      float mx = fmaxf(fmaxf(pmax[qq][0], pmax[qq][1]), fmaxf(pmax[qq][2], pmax[qq][3]));
      float ev = __builtin_amdgcn_exp2f((sc[qq] - mx) * LOG2E_F);
      attn_lds[qq][tk] = ev;
      float s = ev;
      #pragma unroll
      for (int mask = 32; mask >= 1; mask >>= 1) s += __shfl_xor(s, mask);
      if ((t & 63) == 0) psum[qq][wid] = s;
    }
  }
  __syncthreads();

  float rs[QB];
  #pragma unroll
  for (int qq = 0; qq < QB; qq++)
    rs[qq] = __builtin_amdgcn_rcpf(psum[qq][0] + psum[qq][1] + psum[qq][2] + psum[qq][3]);

  // ---- PV: thread (p = t>>7, d4 = t&127) owns dv[4*d4..4*d4+3], k in p-quarter
  const int p  = t >> 7;
  const int d4 = t & 127;
  float4 acc[QB];
  #pragma unroll
  for (int qq = 0; qq < QB; qq++) acc[qq] = make_float4(0.f, 0.f, 0.f, 0.f);
  const float4* vp = (const float4*)(values + (size_t)b * K_ * DV_) + d4;
  const int kbase = p * 64;
  #pragma unroll 2
  for (int kk = 0; kk < 64; kk++) {
    const int k = kbase + kk;
    float4 v = vp[(size_t)k * (DV_ / 4)];
    #pragma unroll
    for (int qq = 0; qq < QB; qq++) {
      float a = attn_lds[qq][k];
      acc[qq].x = fmaf(a, v.x, acc[qq].x);
      acc[qq].y = fmaf(a, v.y, acc[qq].y);
      acc[qq].z = fmaf(a, v.z, acc[qq].z);
      acc[qq].w = fmaf(a, v.w, acc[qq].w);
    }
  }
  // partials from quarters 1..3 -> LDS, quarter 0 combines + writes
  if (p > 0) {
    #pragma unroll
    for (int qq = 0; qq < QB; qq++)
      ((float4*)scratch)[((p - 1) * QB + qq) * 128 + d4] = acc[qq];
  }
  __syncthreads();
  if (p == 0) {
    #pragma unroll
    for (int qq = 0; qq < QB; qq++) {
      float4 a1 = ((float4*)scratch)[(0 * QB + qq) * 128 + d4];
      float4 a2 = ((float4*)scratch)[(1 * QB + qq) * 128 + d4];
      float4 a3 = ((float4*)scratch)[(2 * QB + qq) * 128 + d4];
      float4 o;
      o.x = (acc[qq].x + a1.x + a2.x + a3.x) * rs[qq];
      o.y = (acc[qq].y + a1.y + a2.y + a3.y) * rs[qq];
      o.z = (acc[qq].z + a1.z + a2.z + a3.z) * rs[qq];
      o.w = (acc[qq].w + a1.w + a2.w + a3.w) * rs[qq];
      *(float4*)&out[((size_t)(b * Q_ + q0 + qq)) * DV_ + d4 * 4] = o;
    }
  }
}

extern "C" void kernel_launch(void* const* d_in, const int* in_sizes, int n_in,
                              void* d_out, int out_size, void* d_ws, size_t ws_size,
                              hipStream_t stream) {
  const float* queries = (const float*)d_in[0];  // [8,256,256]
  const float* keys    = (const float*)d_in[1];  // [8,256,256]
  const float* values  = (const float*)d_in[2];  // [8,256,512]
  const float* W_q     = (const float*)d_in[3];  // [256,256]
  const float* W_k     = (const float*)d_in[4];  // [256,256]
  const float* w_v     = (const float*)d_in[5];  // [256]
  float* out = (float*)d_out;

  float* qh  = (float*)d_ws;                     // [8][256][256] = 2 MB
  float* khT = qh + (size_t)B_ * Q_ * H_;        // [8][256][256] = 2 MB

  dim3 pgrid(4, 4, 16), pblk(256);
  proj_kernel<<<pgrid, pblk, 0, stream>>>(queries, keys, W_q, W_k, qh, khT);

  dim3 agrid(Q_ / QB, B_), ablk(512);
  attn_kernel<<<agrid, ablk, 0, stream>>>(qh, khT, w_v, values, out);
}

// Round 4
// 61.555 us; speedup vs baseline: 1.8346x; 1.0537x over previous
//
#include <hip/hip_runtime.h>
#include <hip/hip_bf16.h>

// Problem dims (fixed): B=8, Q=256, K=256, D=256, H=256, DV=512
#define B_  8
#define Q_  256
#define K_  256
#define D_  256
#define H_  256
#define DV_ 512
#define QB  4            // q-rows per attn block

#define SCALE_2LOG2E 2.8853900817779268f   // 2*log2(e): exp(2x) = 2^(x*this)
#define LOG2E_F      1.4426950408889634f

// ---------------------------------------------------------------------------
// Kernel 1: projections.
//   qh [B][Q][H]  = (queries @ W_q) * 2log2e
//   khT[B][H][K]  = (keys    @ W_k)^T * 2log2e
// A-operand staged TRANSPOSED in LDS ([d][row]) so the compute loop reads both
// operands as float4 (32 B / 16 FMA per thread per d  ->  LDS-BW ~64cyc/d/CU).
// grid (4,4,16): x -> 64-chunk of Q (or K), y -> 64-chunk of H, z: b + 8*path
// ---------------------------------------------------------------------------
__global__ __launch_bounds__(256) void proj_kernel(
    const float* __restrict__ queries, const float* __restrict__ keys,
    const float* __restrict__ Wq, const float* __restrict__ Wk,
    float* __restrict__ qh, float* __restrict__ khT) {
  const int tid = threadIdx.x;
  const int m0 = blockIdx.x * 64;          // q-rows (qpath) or k-cols (kpath)
  const int h0 = blockIdx.y * 64;
  const int b  = blockIdx.z & 7;
  const bool kpath = blockIdx.z >= 8;

  __shared__ float As[64][68];             // [d][row]: qpath row=q, kpath row=h
  __shared__ float Bs[64][68];             // [d][col]: qpath col=h, kpath col=k

  const int lr = tid >> 4;                 // 0..15 (load row)
  const int lc = (tid & 15) << 2;          // 0,4,...,60 (load col, float4)
  const int r0 = (tid & 15) << 2;          // micro-tile rows
  const int c0 = (tid >> 4) << 2;          // micro-tile cols

  float acc[4][4] = {};

  for (int kk = 0; kk < D_; kk += 64) {
    if (!kpath) {
      #pragma unroll
      for (int i = 0; i < 4; i++) {
        const int row = lr + i * 16;
        // As[d][q] <- queries[b][m0+row][kk+lc+j]  (transpose scatter)
        float4 va = *(const float4*)&queries[((size_t)(b * Q_ + m0 + row)) * D_ + kk + lc];
        As[lc + 0][row] = va.x; As[lc + 1][row] = va.y;
        As[lc + 2][row] = va.z; As[lc + 3][row] = va.w;
        // Bs[d][h] <- Wq[kk+row][h0+lc]  (direct float4)
        float4 vb = *(const float4*)&Wq[((size_t)(kk + row)) * H_ + h0 + lc];
        *(float4*)&Bs[row][lc] = vb;
      }
    } else {
      #pragma unroll
      for (int i = 0; i < 4; i++) {
        const int row = lr + i * 16;
        // As[d][h] <- Wk[kk+row][h0+lc]  (direct float4)
        float4 va = *(const float4*)&Wk[((size_t)(kk + row)) * H_ + h0 + lc];
        *(float4*)&As[row][lc] = va;
        // Bs[d][k] <- keys[b][m0+row][kk+lc+j]  (transpose scatter)
        float4 vb = *(const float4*)&keys[((size_t)(b * K_ + m0 + row)) * D_ + kk + lc];
        Bs[lc + 0][row] = vb.x; Bs[lc + 1][row] = vb.y;
        Bs[lc + 2][row] = vb.z; Bs[lc + 3][row] = vb.w;
      }
    }
    __syncthreads();

    #pragma unroll 8
    for (int d = 0; d < 64; d++) {
      float4 av = *(const float4*)&As[d][r0];
      float4 bv = *(const float4*)&Bs[d][c0];
      acc[0][0] = fmaf(av.x, bv.x, acc[0][0]); acc[0][1] = fmaf(av.x, bv.y, acc[0][1]);
      acc[0][2] = fmaf(av.x, bv.z, acc[0][2]); acc[0][3] = fmaf(av.x, bv.w, acc[0][3]);
      acc[1][0] = fmaf(av.y, bv.x, acc[1][0]); acc[1][1] = fmaf(av.y, bv.y, acc[1][1]);
      acc[1][2] = fmaf(av.y, bv.z, acc[1][2]); acc[1][3] = fmaf(av.y, bv.w, acc[1][3]);
      acc[2][0] = fmaf(av.z, bv.x, acc[2][0]); acc[2][1] = fmaf(av.z, bv.y, acc[2][1]);
      acc[2][2] = fmaf(av.z, bv.z, acc[2][2]); acc[2][3] = fmaf(av.z, bv.w, acc[2][3]);
      acc[3][0] = fmaf(av.w, bv.x, acc[3][0]); acc[3][1] = fmaf(av.w, bv.y, acc[3][1]);
      acc[3][2] = fmaf(av.w, bv.z, acc[3][2]); acc[3][3] = fmaf(av.w, bv.w, acc[3][3]);
    }
    __syncthreads();
  }

  float* dst = kpath ? khT : qh;
  // qpath: dst[b][m0+r0+i][h0+c0+j]; kpath: dst[b][h0+r0+i][m0+c0+j]
  const int ro = kpath ? h0 : m0, co = kpath ? m0 : h0;
  #pragma unroll
  for (int i = 0; i < 4; i++) {
    float4 v = make_float4(acc[i][0] * SCALE_2LOG2E, acc[i][1] * SCALE_2LOG2E,
                           acc[i][2] * SCALE_2LOG2E, acc[i][3] * SCALE_2LOG2E);
    *(float4*)&dst[((size_t)(b * 256 + ro + r0 + i)) * 256 + co + c0] = v;
  }
}

// ---------------------------------------------------------------------------
// Kernel 2: fused scores + softmax + PV.
//   score'[b,q,k] = sum_h (-2*w_v[h]) / (2^(qh'+kh') + 1)   (const term dropped)
// 1024 threads = 16 waves per block, QB=4, grid (64,8) = 512 blocks
//   -> exactly 2 blocks/CU = 32 waves/CU (100% of wave slots).
// Score: 4-way h-split (quarter = t>>8 owns 64 h), thread owns k = t&255.
// PV: 4-way k-split (p = t>>8) x float2-dv (d2 = t&255), LDS combine.
// ---------------------------------------------------------------------------
__global__ __launch_bounds__(1024) void attn_kernel(
    const float* __restrict__ qh, const float* __restrict__ khT,
    const float* __restrict__ wv, const float* __restrict__ values,
    float* __restrict__ out) {
  const int t   = threadIdx.x;
  const int qtr = t >> 8;       // h-quarter (score) / k-quarter (PV)
  const int tk  = t & 255;      // owned k (score) / dv-pair (PV)
  const int b   = blockIdx.y;
  const int q0  = blockIdx.x * QB;

  __shared__ float qh_t[H_][QB];          // 4 KB  [h][qq], pre-scaled
  __shared__ float wv_lds[H_];            // 1 KB  (-2*wv)
  __shared__ float attn_t[K_][QB];        // 4 KB  [k][qq]
  __shared__ float scratch[3 * QB * 512]; // 24 KB: s2 partials / PV partials
  __shared__ float pmax[QB][4];
  __shared__ float psum[QB][4];

  // ---- stage qh rows (transposed) + wv ----
  if (t < H_) {
    const float* qs = qh + ((size_t)(b * Q_ + q0)) * H_ + t;
    float4 v = make_float4(qs[0], qs[H_], qs[2 * H_], qs[3 * H_]);
    *(float4*)&qh_t[t][0] = v;
    wv_lds[t] = -2.0f * wv[t];
  }
  __syncthreads();

  // ---- score partials: s2[qq] over my 64-h quarter, k = tk ----
  float s2[QB] = {};
  const int hbase = qtr * 64;
  const float* kp = khT + (size_t)b * H_ * K_ + (size_t)hbase * K_ + tk;
  #pragma unroll 2
  for (int hh = 0; hh < 64; hh++) {
    float khv = kp[(size_t)hh * K_];
    float wvh = wv_lds[hbase + hh];
    float4 qv = *(const float4*)&qh_t[hbase + hh][0];
    float e0 = __builtin_amdgcn_exp2f(qv.x + khv);
    float e1 = __builtin_amdgcn_exp2f(qv.y + khv);
    float e2 = __builtin_amdgcn_exp2f(qv.z + khv);
    float e3 = __builtin_amdgcn_exp2f(qv.w + khv);
    s2[0] = fmaf(wvh, __builtin_amdgcn_rcpf(e0 + 1.0f), s2[0]);
    s2[1] = fmaf(wvh, __builtin_amdgcn_rcpf(e1 + 1.0f), s2[1]);
    s2[2] = fmaf(wvh, __builtin_amdgcn_rcpf(e2 + 1.0f), s2[2]);
    s2[3] = fmaf(wvh, __builtin_amdgcn_rcpf(e3 + 1.0f), s2[3]);
  }
  if (qtr > 0) {
    #pragma unroll
    for (int qq = 0; qq < QB; qq++)
      scratch[((qtr - 1) * QB + qq) * K_ + tk] = s2[qq];
  }
  __syncthreads();

  // ---- softmax over k (quarter 0 only; 4 waves own k = tk) ----
  float sc[QB];
  const int wid = t >> 6;       // 0..3 within quarter 0
  if (qtr == 0) {
    #pragma unroll
    for (int qq = 0; qq < QB; qq++) {
      sc[qq] = s2[qq] + scratch[(0 * QB + qq) * K_ + tk]
                      + scratch[(1 * QB + qq) * K_ + tk]
                      + scratch[(2 * QB + qq) * K_ + tk];
      float m = sc[qq];
      #pragma unroll
      for (int mask = 32; mask >= 1; mask >>= 1) m = fmaxf(m, __shfl_xor(m, mask));
      if ((t & 63) == 0) pmax[qq][wid] = m;
    }
  }
  __syncthreads();
  if (qtr == 0) {
    #pragma unroll
    for (int qq = 0; qq < QB; qq++) {
      float mx = fmaxf(fmaxf(pmax[qq][0], pmax[qq][1]), fmaxf(pmax[qq][2], pmax[qq][3]));
      float ev = __builtin_amdgcn_exp2f((sc[qq] - mx) * LOG2E_F);
      attn_t[tk][qq] = ev;
      float s = ev;
      #pragma unroll
      for (int mask = 32; mask >= 1; mask >>= 1) s += __shfl_xor(s, mask);
      if ((t & 63) == 0) psum[qq][wid] = s;
    }
  }
  __syncthreads();

  float rs[QB];
  #pragma unroll
  for (int qq = 0; qq < QB; qq++)
    rs[qq] = __builtin_amdgcn_rcpf(psum[qq][0] + psum[qq][1] + psum[qq][2] + psum[qq][3]);

  // ---- PV: quarter qtr owns k in [64*qtr, 64*qtr+64); thread owns dv pair tk
  float2 acc[QB];
  #pragma unroll
  for (int qq = 0; qq < QB; qq++) acc[qq] = make_float2(0.f, 0.f);
  const float2* vp = (const float2*)(values + (size_t)b * K_ * DV_) + tk;
  const int kbase = qtr * 64;
  #pragma unroll 2
  for (int kk = 0; kk < 64; kk++) {
    const int k = kbase + kk;
    float2 v = vp[(size_t)k * (DV_ / 2)];
    float4 a = *(const float4*)&attn_t[k][0];
    acc[0].x = fmaf(a.x, v.x, acc[0].x); acc[0].y = fmaf(a.x, v.y, acc[0].y);
    acc[1].x = fmaf(a.y, v.x, acc[1].x); acc[1].y = fmaf(a.y, v.y, acc[1].y);
    acc[2].x = fmaf(a.z, v.x, acc[2].x); acc[2].y = fmaf(a.z, v.y, acc[2].y);
    acc[3].x = fmaf(a.w, v.x, acc[3].x); acc[3].y = fmaf(a.w, v.y, acc[3].y);
  }
  if (qtr > 0) {
    #pragma unroll
    for (int qq = 0; qq < QB; qq++)
      ((float2*)scratch)[((qtr - 1) * QB + qq) * 256 + tk] = acc[qq];
  }
  __syncthreads();
  if (qtr == 0) {
    #pragma unroll
    for (int qq = 0; qq < QB; qq++) {
      float2 a1 = ((float2*)scratch)[(0 * QB + qq) * 256 + tk];
      float2 a2 = ((float2*)scratch)[(1 * QB + qq) * 256 + tk];
      float2 a3 = ((float2*)scratch)[(2 * QB + qq) * 256 + tk];
      float2 o;
      o.x = (acc[qq].x + a1.x + a2.x + a3.x) * rs[qq];
      o.y = (acc[qq].y + a1.y + a2.y + a3.y) * rs[qq];
      *(float2*)&out[((size_t)(b * Q_ + q0 + qq)) * DV_ + 2 * tk] = o;
    }
  }
}

extern "C" void kernel_launch(void* const* d_in, const int* in_sizes, int n_in,
                              void* d_out, int out_size, void* d_ws, size_t ws_size,
                              hipStream_t stream) {
  const float* queries = (const float*)d_in[0];  // [8,256,256]
  const float* keys    = (const float*)d_in[1];  // [8,256,256]
  const float* values  = (const float*)d_in[2];  // [8,256,512]
  const float* W_q     = (const float*)d_in[3];  // [256,256]
  const float* W_k     = (const float*)d_in[4];  // [256,256]
  const float* w_v     = (const float*)d_in[5];  // [256]
  float* out = (float*)d_out;

  float* qh  = (float*)d_ws;                     // [8][256][256] = 2 MB
  float* khT = qh + (size_t)B_ * Q_ * H_;        // [8][256][256] = 2 MB

  dim3 pgrid(4, 4, 16), pblk(256);
  proj_kernel<<<pgrid, pblk, 0, stream>>>(queries, keys, W_q, W_k, qh, khT);

  dim3 agrid(Q_ / QB, B_), ablk(1024);
  attn_kernel<<<agrid, ablk, 0, stream>>>(qh, khT, w_v, values, out);
}

// Round 5
// 52.535 us; speedup vs baseline: 2.1496x; 1.1717x over previous
//
#include <hip/hip_runtime.h>
#include <hip/hip_bf16.h>

// Problem dims (fixed): B=8, Q=256, K=256, D=256, H=256, DV=512
#define B_  8
#define Q_  256
#define K_  256
#define D_  256
#define H_  256
#define DV_ 512
#define QB  4            // q-rows per attn block

#define SCALE_2LOG2E 2.8853900817779268f   // 2*log2(e): exp(2x) = 2^(x*this)
#define LOG2E_F      1.4426950408889634f

// ---------------------------------------------------------------------------
// Kernel 1: projections + EXPONENTIATION (exp factorization):
//   Eq [B][Q][H]  = 2^((queries @ W_q) * 2log2e)     = e^(2*qh)
//   EkT[B][H][K]  = 2^((keys    @ W_k)^T * 2log2e)   = e^(2*kh), transposed
// Then sigmoid denominator in kernel 2 is 1 + Eq*Ek  (ONE trans op instead of
// two: the exp2 moved here, amortized 256x).
// A-operand staged TRANSPOSED in LDS ([d][row]) so the compute loop reads both
// operands as float4.
// grid (4,4,16): x -> 64-chunk of Q (or K), y -> 64-chunk of H, z: b + 8*path
// ---------------------------------------------------------------------------
__global__ __launch_bounds__(256) void proj_kernel(
    const float* __restrict__ queries, const float* __restrict__ keys,
    const float* __restrict__ Wq, const float* __restrict__ Wk,
    float* __restrict__ Eq, float* __restrict__ EkT) {
  const int tid = threadIdx.x;
  const int m0 = blockIdx.x * 64;          // q-rows (qpath) or k-cols (kpath)
  const int h0 = blockIdx.y * 64;
  const int b  = blockIdx.z & 7;
  const bool kpath = blockIdx.z >= 8;

  __shared__ float As[64][68];             // [d][row]: qpath row=q, kpath row=h
  __shared__ float Bs[64][68];             // [d][col]: qpath col=h, kpath col=k

  const int lr = tid >> 4;                 // 0..15 (load row)
  const int lc = (tid & 15) << 2;          // 0,4,...,60 (load col, float4)
  const int r0 = (tid & 15) << 2;          // micro-tile rows
  const int c0 = (tid >> 4) << 2;          // micro-tile cols

  float acc[4][4] = {};

  for (int kk = 0; kk < D_; kk += 64) {
    if (!kpath) {
      #pragma unroll
      for (int i = 0; i < 4; i++) {
        const int row = lr + i * 16;
        // As[d][q] <- queries[b][m0+row][kk+lc+j]  (transpose scatter)
        float4 va = *(const float4*)&queries[((size_t)(b * Q_ + m0 + row)) * D_ + kk + lc];
        As[lc + 0][row] = va.x; As[lc + 1][row] = va.y;
        As[lc + 2][row] = va.z; As[lc + 3][row] = va.w;
        // Bs[d][h] <- Wq[kk+row][h0+lc]  (direct float4)
        float4 vb = *(const float4*)&Wq[((size_t)(kk + row)) * H_ + h0 + lc];
        *(float4*)&Bs[row][lc] = vb;
      }
    } else {
      #pragma unroll
      for (int i = 0; i < 4; i++) {
        const int row = lr + i * 16;
        // As[d][h] <- Wk[kk+row][h0+lc]  (direct float4)
        float4 va = *(const float4*)&Wk[((size_t)(kk + row)) * H_ + h0 + lc];
        *(float4*)&As[row][lc] = va;
        // Bs[d][k] <- keys[b][m0+row][kk+lc+j]  (transpose scatter)
        float4 vb = *(const float4*)&keys[((size_t)(b * K_ + m0 + row)) * D_ + kk + lc];
        Bs[lc + 0][row] = vb.x; Bs[lc + 1][row] = vb.y;
        Bs[lc + 2][row] = vb.z; Bs[lc + 3][row] = vb.w;
      }
    }
    __syncthreads();

    #pragma unroll 8
    for (int d = 0; d < 64; d++) {
      float4 av = *(const float4*)&As[d][r0];
      float4 bv = *(const float4*)&Bs[d][c0];
      acc[0][0] = fmaf(av.x, bv.x, acc[0][0]); acc[0][1] = fmaf(av.x, bv.y, acc[0][1]);
      acc[0][2] = fmaf(av.x, bv.z, acc[0][2]); acc[0][3] = fmaf(av.x, bv.w, acc[0][3]);
      acc[1][0] = fmaf(av.y, bv.x, acc[1][0]); acc[1][1] = fmaf(av.y, bv.y, acc[1][1]);
      acc[1][2] = fmaf(av.y, bv.z, acc[1][2]); acc[1][3] = fmaf(av.y, bv.w, acc[1][3]);
      acc[2][0] = fmaf(av.z, bv.x, acc[2][0]); acc[2][1] = fmaf(av.z, bv.y, acc[2][1]);
      acc[2][2] = fmaf(av.z, bv.z, acc[2][2]); acc[2][3] = fmaf(av.z, bv.w, acc[2][3]);
      acc[3][0] = fmaf(av.w, bv.x, acc[3][0]); acc[3][1] = fmaf(av.w, bv.y, acc[3][1]);
      acc[3][2] = fmaf(av.w, bv.z, acc[3][2]); acc[3][3] = fmaf(av.w, bv.w, acc[3][3]);
    }
    __syncthreads();
  }

  float* dst = kpath ? EkT : Eq;
  // qpath: dst[b][m0+r0+i][h0+c0+j]; kpath: dst[b][h0+r0+i][m0+c0+j]
  const int ro = kpath ? h0 : m0, co = kpath ? m0 : h0;
  #pragma unroll
  for (int i = 0; i < 4; i++) {
    float4 v;
    v.x = __builtin_amdgcn_exp2f(acc[i][0] * SCALE_2LOG2E);
    v.y = __builtin_amdgcn_exp2f(acc[i][1] * SCALE_2LOG2E);
    v.z = __builtin_amdgcn_exp2f(acc[i][2] * SCALE_2LOG2E);
    v.w = __builtin_amdgcn_exp2f(acc[i][3] * SCALE_2LOG2E);
    *(float4*)&dst[((size_t)(b * 256 + ro + r0 + i)) * 256 + co + c0] = v;
  }
}

// ---------------------------------------------------------------------------
// Kernel 2: fused scores + softmax + PV.
//   sigma = 1/(1 + Eq[q][h]*Ek[h][k]);  score'[b,q,k] = sum_h (-2*w_v[h])*sigma
//   (exp factorization: 1 rcp per element, no per-element exp)
// 1024 threads = 16 waves per block, QB=4, grid (64,8) = 512 blocks
//   -> exactly 2 blocks/CU = 32 waves/CU.
// Score: 4-way h-split (quarter = t>>8 owns 64 h), thread owns k = t&255.
// PV: 4-way k-split x float2-dv, LDS combine.
// ---------------------------------------------------------------------------
__global__ __launch_bounds__(1024) void attn_kernel(
    const float* __restrict__ Eq, const float* __restrict__ EkT,
    const float* __restrict__ wv, const float* __restrict__ values,
    float* __restrict__ out) {
  const int t   = threadIdx.x;
  const int qtr = t >> 8;       // h-quarter (score) / k-quarter (PV)
  const int tk  = t & 255;      // owned k (score) / dv-pair (PV)
  const int b   = blockIdx.y;
  const int q0  = blockIdx.x * QB;

  __shared__ float eq_t[H_][QB];          // 4 KB  [h][qq]
  __shared__ float wv_lds[H_];            // 1 KB  (-2*wv)
  __shared__ float attn_t[K_][QB];        // 4 KB  [k][qq]
  __shared__ float scratch[3 * QB * 512]; // 24 KB: s2 partials / PV partials
  __shared__ float pmax[QB][4];
  __shared__ float psum[QB][4];

  // ---- stage Eq rows (transposed) + wv ----
  if (t < H_) {
    const float* qs = Eq + ((size_t)(b * Q_ + q0)) * H_ + t;
    float4 v = make_float4(qs[0], qs[H_], qs[2 * H_], qs[3 * H_]);
    *(float4*)&eq_t[t][0] = v;
    wv_lds[t] = -2.0f * wv[t];
  }
  __syncthreads();

  // ---- score partials: s2[qq] over my 64-h quarter, k = tk ----
  float s2[QB] = {};
  const int hbase = qtr * 64;
  const float* kp = EkT + (size_t)b * H_ * K_ + (size_t)hbase * K_ + tk;
  #pragma unroll 2
  for (int hh = 0; hh < 64; hh++) {
    float ekv = kp[(size_t)hh * K_];
    float wvh = wv_lds[hbase + hh];
    float4 eq = *(const float4*)&eq_t[hbase + hh][0];
    float d0 = fmaf(eq.x, ekv, 1.0f);
    float d1 = fmaf(eq.y, ekv, 1.0f);
    float d2 = fmaf(eq.z, ekv, 1.0f);
    float d3 = fmaf(eq.w, ekv, 1.0f);
    s2[0] = fmaf(wvh, __builtin_amdgcn_rcpf(d0), s2[0]);
    s2[1] = fmaf(wvh, __builtin_amdgcn_rcpf(d1), s2[1]);
    s2[2] = fmaf(wvh, __builtin_amdgcn_rcpf(d2), s2[2]);
    s2[3] = fmaf(wvh, __builtin_amdgcn_rcpf(d3), s2[3]);
  }
  if (qtr > 0) {
    #pragma unroll
    for (int qq = 0; qq < QB; qq++)
      scratch[((qtr - 1) * QB + qq) * K_ + tk] = s2[qq];
  }
  __syncthreads();

  // ---- softmax over k (quarter 0 only; 4 waves own k = tk) ----
  float sc[QB];
  const int wid = t >> 6;       // 0..3 within quarter 0
  if (qtr == 0) {
    #pragma unroll
    for (int qq = 0; qq < QB; qq++) {
      sc[qq] = s2[qq] + scratch[(0 * QB + qq) * K_ + tk]
                      + scratch[(1 * QB + qq) * K_ + tk]
                      + scratch[(2 * QB + qq) * K_ + tk];
      float m = sc[qq];
      #pragma unroll
      for (int mask = 32; mask >= 1; mask >>= 1) m = fmaxf(m, __shfl_xor(m, mask));
      if ((t & 63) == 0) pmax[qq][wid] = m;
    }
  }
  __syncthreads();
  if (qtr == 0) {
    #pragma unroll
    for (int qq = 0; qq < QB; qq++) {
      float mx = fmaxf(fmaxf(pmax[qq][0], pmax[qq][1]), fmaxf(pmax[qq][2], pmax[qq][3]));
      float ev = __builtin_amdgcn_exp2f((sc[qq] - mx) * LOG2E_F);
      attn_t[tk][qq] = ev;
      float s = ev;
      #pragma unroll
      for (int mask = 32; mask >= 1; mask >>= 1) s += __shfl_xor(s, mask);
      if ((t & 63) == 0) psum[qq][wid] = s;
    }
  }
  __syncthreads();

  float rs[QB];
  #pragma unroll
  for (int qq = 0; qq < QB; qq++)
    rs[qq] = __builtin_amdgcn_rcpf(psum[qq][0] + psum[qq][1] + psum[qq][2] + psum[qq][3]);

  // ---- PV: quarter qtr owns k in [64*qtr, 64*qtr+64); thread owns dv pair tk
  float2 acc[QB];
  #pragma unroll
  for (int qq = 0; qq < QB; qq++) acc[qq] = make_float2(0.f, 0.f);
  const float2* vp = (const float2*)(values + (size_t)b * K_ * DV_) + tk;
  const int kbase = qtr * 64;
  #pragma unroll 2
  for (int kk = 0; kk < 64; kk++) {
    const int k = kbase + kk;
    float2 v = vp[(size_t)k * (DV_ / 2)];
    float4 a = *(const float4*)&attn_t[k][0];
    acc[0].x = fmaf(a.x, v.x, acc[0].x); acc[0].y = fmaf(a.x, v.y, acc[0].y);
    acc[1].x = fmaf(a.y, v.x, acc[1].x); acc[1].y = fmaf(a.y, v.y, acc[1].y);
    acc[2].x = fmaf(a.z, v.x, acc[2].x); acc[2].y = fmaf(a.z, v.y, acc[2].y);
    acc[3].x = fmaf(a.w, v.x, acc[3].x); acc[3].y = fmaf(a.w, v.y, acc[3].y);
  }
  if (qtr > 0) {
    #pragma unroll
    for (int qq = 0; qq < QB; qq++)
      ((float2*)scratch)[((qtr - 1) * QB + qq) * 256 + tk] = acc[qq];
  }
  __syncthreads();
  if (qtr == 0) {
    #pragma unroll
    for (int qq = 0; qq < QB; qq++) {
      float2 a1 = ((float2*)scratch)[(0 * QB + qq) * 256 + tk];
      float2 a2 = ((float2*)scratch)[(1 * QB + qq) * 256 + tk];
      float2 a3 = ((float2*)scratch)[(2 * QB + qq) * 256 + tk];
      float2 o;
      o.x = (acc[qq].x + a1.x + a2.x + a3.x) * rs[qq];
      o.y = (acc[qq].y + a1.y + a2.y + a3.y) * rs[qq];
      *(float2*)&out[((size_t)(b * Q_ + q0 + qq)) * DV_ + 2 * tk] = o;
    }
  }
}

extern "C" void kernel_launch(void* const* d_in, const int* in_sizes, int n_in,
                              void* d_out, int out_size, void* d_ws, size_t ws_size,
                              hipStream_t stream) {
  const float* queries = (const float*)d_in[0];  // [8,256,256]
  const float* keys    = (const float*)d_in[1];  // [8,256,256]
  const float* values  = (const float*)d_in[2];  // [8,256,512]
  const float* W_q     = (const float*)d_in[3];  // [256,256]
  const float* W_k     = (const float*)d_in[4];  // [256,256]
  const float* w_v     = (const float*)d_in[5];  // [256]
  float* out = (float*)d_out;

  float* Eq  = (float*)d_ws;                     // [8][256][256] = 2 MB
  float* EkT = Eq + (size_t)B_ * Q_ * H_;        // [8][256][256] = 2 MB

  dim3 pgrid(4, 4, 16), pblk(256);
  proj_kernel<<<pgrid, pblk, 0, stream>>>(queries, keys, W_q, W_k, Eq, EkT);

  dim3 agrid(Q_ / QB, B_), ablk(1024);
  attn_kernel<<<agrid, ablk, 0, stream>>>(Eq, EkT, w_v, values, out);
}